// Round 6
// baseline (326.700 us; speedup 1.0000x reference)
//
#include <hip/hip_runtime.h>
#include <hip/hip_bf16.h>

typedef __hip_bfloat16 bf16;
typedef __bf16 bf16x8 __attribute__((ext_vector_type(8)));
typedef float f32x4 __attribute__((ext_vector_type(4)));

#define NEG_SLOPE 0.2f
#define F32_THRESH 256

// ---------------- helpers ----------------------------------------------------

__device__ __forceinline__ bool is_f32(const int* fcnt) { return *fcnt > F32_THRESH; }

__device__ __forceinline__ float ld_f(const void* p, long long i, bool f32) {
    return f32 ? ((const float*)p)[i] : __bfloat162float(((const bf16*)p)[i]);
}

__device__ __forceinline__ float b2f(unsigned hs) {
    return __uint_as_float(hs << 16);
}

__device__ __forceinline__ unsigned pack_bf2(float a, float b) {
    union { bf16 h[2]; unsigned u; } p;
    p.h[0] = __float2bfloat16(a);
    p.h[1] = __float2bfloat16(b);
    return p.u;
}

__device__ __forceinline__ void load_lds16(const void* g, void* l) {
    __builtin_amdgcn_global_load_lds(
        (const __attribute__((address_space(1))) void*)g,
        (__attribute__((address_space(3))) void*)l, 16, 0, 0);
}

// ---------------- probe: dtype sniff + int-width detect, one kernel ---------

__global__ void k_probe(const unsigned* xw, long long nw, const int* idx, int n_half,
                        int* cnt, int* iflag) {
    long long t = blockIdx.x * (long long)blockDim.x + threadIdx.x;
    long long stride = (long long)gridDim.x * blockDim.x;
    int c = 0;
    for (long long i = t; i < nw; i += stride)
        if ((xw[i] & 0x7F80u) == 0x7F80u) c++;
    if (c) atomicAdd(cnt, c);
    int any = 0;
    for (long long i = t; i < n_half; i += stride)
        if (idx[2 * i + 1] != 0) any = 1;
    if (any) atomicOr(iflag, 1);
}

// ---------------- bf16 conversion (only runs when input is fp32) ------------

__global__ void k_tobf16(const void* src, const int* fcnt, bf16* dst,
                         long long n_valid, long long n_total) {
    if (!is_f32(fcnt)) return;  // bf16 input: gemm reads source directly
    long long t = blockIdx.x * (long long)blockDim.x + threadIdx.x;
    long long n8 = n_total / 8;
    for (long long i = t; i < n8; i += (long long)gridDim.x * blockDim.x) {
        long long b = i * 8;
        uint4 out;
        if (b + 8 <= n_valid) {
            const float4* s4 = (const float4*)src;
            float4 x0 = s4[i * 2], x1 = s4[i * 2 + 1];
            out.x = pack_bf2(x0.x, x0.y);
            out.y = pack_bf2(x0.z, x0.w);
            out.z = pack_bf2(x1.x, x1.y);
            out.w = pack_bf2(x1.z, x1.w);
        } else {
            bf16 tmp[8];
#pragma unroll
            for (int j = 0; j < 8; j++) {
                long long k = b + j;
                tmp[j] = (k < n_valid) ? __float2bfloat16(ld_f(src, k, true))
                                       : __float2bfloat16(0.f);
            }
            out = *(uint4*)tmp;
        }
        ((uint4*)dst)[i] = out;
    }
}

// tail pad: rows [R0, R0+128) of x -> tail buffer (zero beyond Nrows). Both dtypes.
__global__ void k_tail(const void* x, const int* fcnt, bf16* tail, int R0, int Nrows, int K) {
    bool f32 = is_f32(fcnt);
    int total = 128 * K;
    for (int i = blockIdx.x * blockDim.x + threadIdx.x; i < total;
         i += gridDim.x * blockDim.x) {
        int r = i / K;
        long long src = (long long)(R0 + r) * K + (i - r * K);
        tail[i] = (R0 + r < Nrows) ? __float2bfloat16(ld_f(x, src, f32))
                                   : __float2bfloat16(0.f);
    }
}

// ---------------- CSR build (hardened) --------------------------------------

__device__ __forceinline__ int edge_val(const void* idx, long long i, int is64) {
    return is64 ? (int)((const long long*)idx)[i] : ((const int*)idx)[i];
}

__global__ void k_count(const void* idx, const int* iflag, int E0, int N, int* deg) {
    int e = blockIdx.x * blockDim.x + threadIdx.x;
    if (e >= E0 + N) return;
    int is64 = (*iflag == 0);
    int d = (e < E0) ? edge_val(idx, (long long)E0 + e, is64) : (e - E0);
    if ((unsigned)d >= (unsigned)N) d = 0;
    atomicAdd(&deg[d], 1);
}

__global__ __launch_bounds__(1024) void k_scan(const int* deg, int* rowptr, int N) {
    __shared__ int part[1024];
    int t = threadIdx.x;
    int chunk = (N + 1023) / 1024;
    int s = t * chunk, e = min(N, s + chunk);
    int sum = 0;
    for (int i = s; i < e; i++) sum += deg[i];
    part[t] = sum;
    __syncthreads();
    for (int off = 1; off < 1024; off <<= 1) {
        int v = (t >= off) ? part[t - off] : 0;
        __syncthreads();
        part[t] += v;
        __syncthreads();
    }
    int run = (t == 0) ? 0 : part[t - 1];
    for (int i = s; i < e; i++) { rowptr[i] = run; run += deg[i]; }
    if (t == 1023) rowptr[N] = part[1023];
}

__global__ void k_scatter(const void* idx, const int* iflag, int E0, int N,
                          const int* rowptr, int* cursor, int* csr_src) {
    int e = blockIdx.x * blockDim.x + threadIdx.x;
    if (e >= E0 + N) return;
    int is64 = (*iflag == 0);
    int s, d;
    if (e < E0) {
        s = edge_val(idx, e, is64);
        d = edge_val(idx, (long long)E0 + e, is64);
    } else {
        s = d = e - E0;
    }
    if ((unsigned)s >= (unsigned)N) s = 0;
    if ((unsigned)d >= (unsigned)N) d = 0;
    int pos = rowptr[d] + atomicAdd(&cursor[d], 1);
    if ((unsigned)pos < (unsigned)(E0 + N)) csr_src[pos] = s;
}

// ---------------- weight transpose ------------------------------------------

__global__ void k_transpose(const void* W, const int* fcnt, bf16* Wt, int K, int N) {
    int i = blockIdx.x * blockDim.x + threadIdx.x;
    if (i >= K * N) return;
    bool f32 = is_f32(fcnt);
    int k = i / N, n = i % N;
    Wt[(size_t)n * K + k] = __float2bfloat16(ld_f(W, i, f32));
}

// ---------------- attention logits (vectorized) -----------------------------

__global__ void k_al(const bf16* __restrict__ h, const void* a_s, const void* a_d,
                     const int* fcnt, float* als, float* ald, int N, int H) {
    __shared__ float sa[512], sd[512];
    const int HC = H * 128;
    bool f32 = is_f32(fcnt);
    for (int i = threadIdx.x; i < HC; i += blockDim.x) {
        sa[i] = ld_f(a_s, i, f32);
        sd[i] = ld_f(a_d, i, f32);
    }
    __syncthreads();
    int i = blockIdx.x * blockDim.x + threadIdx.x;
    if (i >= N * H) return;
    int n = i / H, hh = i % H;
    const uint4* row = (const uint4*)(h + (size_t)n * HC + hh * 128);
    float s = 0.f, d = 0.f;
#pragma unroll
    for (int q = 0; q < 16; q++) {
        uint4 u = row[q];
        unsigned uu[4] = {u.x, u.y, u.z, u.w};
#pragma unroll
        for (int t = 0; t < 4; t++) {
            float v0 = b2f(uu[t] & 0xFFFFu), v1 = b2f(uu[t] >> 16);
            int c = hh * 128 + q * 8 + t * 2;
            s += v0 * sa[c] + v1 * sa[c + 1];
            d += v0 * sd[c] + v1 * sd[c + 1];
        }
    }
    als[i] = s;
    ald[i] = d;
}

// ---------------- MFMA GEMM (m97-style): C[M,Nn] = A @ Bt^T -----------------
// SEL: A chosen between raw (bf16 input) / converted (fp32 input), last
// m-block reads the 128-row tail-pad buffer instead.

template <int BN, bool SEL>
__global__ __launch_bounds__(256) void k_gemm(const void* Araw, const bf16* Aconv,
                                              const bf16* Atail, const int* fcnt,
                                              const bf16* __restrict__ Bt,
                                              bf16* __restrict__ C,
                                              int M, int Nn, int K, int nfull) {
    constexpr int BM = 128, BK = 32;
    constexpr int NT = BN / 32;
    const int m0 = blockIdx.x * BM;
    const int n0 = blockIdx.y * BN;
    __shared__ __bf16 As[BM][BK];
    __shared__ __bf16 Bs[BN][BK];
    const int tid = threadIdx.x;
    const int wave = tid >> 6;
    const int lane = tid & 63;
    const int wm = (wave & 1) * 64;
    const int wn = (wave >> 1) * (NT * 16);
    const int lm = lane & 15;
    const int quad = lane >> 4;
    const int srow = tid >> 2;
    const int scol = (tid & 3) * 8;

    f32x4 acc[4][NT];
#pragma unroll
    for (int mt = 0; mt < 4; mt++)
#pragma unroll
        for (int nt = 0; nt < NT; nt++) acc[mt][nt] = (f32x4){0.f, 0.f, 0.f, 0.f};

    const bf16* Abase;
    int arow0;
    if (SEL) {
        const bf16* Asel = is_f32(fcnt) ? Aconv : (const bf16*)Araw;
        if ((int)blockIdx.x < nfull) { Abase = Asel; arow0 = m0; }
        else { Abase = Atail; arow0 = 0; }
    } else {
        Abase = (const bf16*)Araw;
        arow0 = m0;
    }

    const char* Ab = (const char*)(Abase + (size_t)(arow0 + srow) * K + scol);
    const char* Bb = (const char*)(Bt + (size_t)(n0 + srow) * K + scol);
    char* ldsA = (char*)&As[0][0] + wave * 1024;
    char* ldsB = (char*)&Bs[0][0] + wave * 1024;
    const size_t rstep = (size_t)64 * K * 2;

    for (int k0 = 0; k0 < K; k0 += BK) {
        __syncthreads();
        const size_t kb = (size_t)k0 * 2;
        load_lds16(Ab + kb, ldsA);
        load_lds16(Ab + kb + rstep, ldsA + 4096);
        load_lds16(Bb + kb, ldsB);
        if (BN == 128) load_lds16(Bb + kb + rstep, ldsB + 4096);
        __syncthreads();
        bf16x8 af[4], bfv[NT];
#pragma unroll
        for (int mt = 0; mt < 4; mt++)
            af[mt] = *(const bf16x8*)&As[wm + mt * 16 + lm][quad * 8];
#pragma unroll
        for (int nt = 0; nt < NT; nt++)
            bfv[nt] = *(const bf16x8*)&Bs[wn + nt * 16 + lm][quad * 8];
#pragma unroll
        for (int mt = 0; mt < 4; mt++)
#pragma unroll
            for (int nt = 0; nt < NT; nt++)
                acc[mt][nt] = __builtin_amdgcn_mfma_f32_16x16x32_bf16(
                    af[mt], bfv[nt], acc[mt][nt], 0, 0, 0);
    }

#pragma unroll
    for (int mt = 0; mt < 4; mt++) {
        int rb = m0 + wm + mt * 16 + quad * 4;
#pragma unroll
        for (int nt = 0; nt < NT; nt++) {
            int col = n0 + wn + nt * 16 + lm;
#pragma unroll
            for (int r = 0; r < 4; r++) {
                int row = rb + r;
                if (row < M) C[(size_t)row * Nn + col] = __float2bfloat16(acc[mt][nt][r]);
            }
        }
    }
}

// ---------------- per-dst aggregation: WAVE-PER-NODE, no LDS, no barrier ----
// Lane owns C/64 channels; every lane sees every edge, so the softmax
// denominator is the lane's own psum — no reduction needed. Weight exp is
// computed inline per head (1 transcendental/edge/lane).

template <int C, int H, bool ELU, bool DYN_OUT>
__global__ __launch_bounds__(256) void k_agg(
    const bf16* __restrict__ feat, const float* __restrict__ als,
    const float* __restrict__ ald, const int* __restrict__ rowptr,
    const int* __restrict__ csr_src, const void* bias, const int* fcnt,
    void* outp, int N, int E) {
    constexpr int CPL = C / 64;
    constexpr int Ch = C / H;
    const int wave = threadIdx.x >> 6;
    const int lane = threadIdx.x & 63;
    const int n = blockIdx.x * 4 + wave;
    if (n >= N) return;
    const int c0 = lane * CPL;
    const int head = c0 / Ch;

    int start = rowptr[n];
    if (start < 0) start = 0;
    int end = rowptr[n + 1];
    if (end > E) end = E;
    int deg = end - start;
    if (deg < 0) deg = 0;

    const float aldn = ald[(size_t)n * H + head];
    float acc[CPL] = {};
    float psum = 0.f;

    auto wfun = [&](int s) {
        float l = als[(size_t)s * H + head] + aldn;
        l = l > 0.f ? l : NEG_SLOPE * l;
        return __expf(fminf(l, 60.f));
    };
    auto body = [&](int s, float wl) {
        const bf16* fr = feat + (size_t)s * C + c0;
        if constexpr (CPL == 8) {
            uint4 u = *(const uint4*)fr;
            unsigned uu[4] = {u.x, u.y, u.z, u.w};
#pragma unroll
            for (int q = 0; q < 4; q++) {
                acc[2 * q] += wl * b2f(uu[q] & 0xFFFFu);
                acc[2 * q + 1] += wl * b2f(uu[q] >> 16);
            }
        } else {
            unsigned u = *(const unsigned*)fr;
            acc[0] += wl * b2f(u & 0xFFFFu);
            acc[1] += wl * b2f(u >> 16);
        }
    };

    int e = 0;
    for (; e + 4 <= deg; e += 4) {
        int i0 = start + e;
        int s0 = csr_src[i0], s1 = csr_src[i0 + 1];
        int s2 = csr_src[i0 + 2], s3 = csr_src[i0 + 3];
        if ((unsigned)s0 >= (unsigned)N) s0 = 0;
        if ((unsigned)s1 >= (unsigned)N) s1 = 0;
        if ((unsigned)s2 >= (unsigned)N) s2 = 0;
        if ((unsigned)s3 >= (unsigned)N) s3 = 0;
        float w0 = wfun(s0), w1 = wfun(s1), w2 = wfun(s2), w3 = wfun(s3);
        psum += w0 + w1 + w2 + w3;
        body(s0, w0);
        body(s1, w1);
        body(s2, w2);
        body(s3, w3);
    }
    for (; e < deg; e++) {
        int s = csr_src[start + e];
        if ((unsigned)s >= (unsigned)N) s = 0;
        float w0 = wfun(s);
        psum += w0;
        body(s, w0);
    }

    const float dn = psum + 1e-16f;
    const bool f32 = is_f32(fcnt);
#pragma unroll
    for (int j = 0; j < CPL; j++) {
        float v = acc[j] / dn + ld_f(bias, c0 + j, f32);
        if (ELU) v = v > 0.f ? v : expf(v) - 1.f;
        size_t oi = (size_t)n * C + c0 + j;
        if (DYN_OUT && f32) ((float*)outp)[oi] = v;
        else ((bf16*)outp)[oi] = __float2bfloat16(v);
    }
}

// ---------------- launch -----------------------------------------------------

extern "C" void kernel_launch(void* const* d_in, const int* in_sizes, int n_in,
                              void* d_out, int out_size, void* d_ws, size_t ws_size,
                              hipStream_t stream) {
    const int N = in_sizes[0] / 512;  // 20000
    const int K = 512;
    const int C1 = 512;
    const int C2 = 128;
    const int H1 = 4;
    const int E0 = in_sizes[1] / 2;   // 320000
    const int E = E0 + N;
    const int Mpad = (N + 127) / 128 * 128;  // 20096
    const int nfull = N / 128;               // 156 full 128-row tiles

    const void* x_raw = d_in[0];
    const void* eidx = d_in[1];
    const void* W1 = d_in[2];
    const void* as1 = d_in[3];
    const void* ad1 = d_in[4];
    const void* b1 = d_in[5];
    const void* W2 = d_in[6];
    const void* as2 = d_in[7];
    const void* ad2 = d_in[8];
    const void* b2 = d_in[9];

    char* ws = (char*)d_ws;
    size_t off = 0;
    auto take = [&](size_t bytes) {
        size_t r = off;
        off += (bytes + 255) & ~(size_t)255;
        return r;
    };
    bf16* xb     = (bf16*)(ws + take((size_t)Mpad * K * 2));  // fp32 path; reused for h2
    bf16* xtail  = (bf16*)(ws + take((size_t)128 * K * 2));
    bf16* h1     = (bf16*)(ws + take((size_t)N * C1 * 2));
    bf16* hagg   = (bf16*)(ws + take((size_t)Mpad * C1 * 2));
    bf16* W1t    = (bf16*)(ws + take((size_t)K * C1 * 2));
    bf16* W2t    = (bf16*)(ws + take((size_t)C1 * C2 * 2));
    float* al1s  = (float*)(ws + take((size_t)N * H1 * 4));
    float* al1d  = (float*)(ws + take((size_t)N * H1 * 4));
    int* rowptr  = (int*)(ws + take((size_t)(N + 1) * 4));
    int* csr_src = (int*)(ws + take((size_t)E * 4));
    // contiguous zero-init: deg(N), cursor(N), iflag, fcnt
    int* deg     = (int*)(ws + take((size_t)(2 * N + 2) * 4));
    int* cursor  = deg + N;
    int* iflag   = deg + 2 * N;
    int* fcnt    = deg + 2 * N + 1;
    bf16* h2     = xb;     // alias: xb dead after gemm1
    float* al2s  = al1s;   // alias: al1 dead after agg1
    float* al2d  = al1d;
    if (off > ws_size) return;

    hipMemsetAsync(deg, 0, (size_t)(2 * N + 2) * 4, stream);
    // hagg pad rows must be zero for gemm2 (agg1 writes only [0,N))
    hipMemsetAsync(hagg + (size_t)N * C1, 0, (size_t)(Mpad - N) * C1 * 2, stream);

    // probes (capped scans)
    long long nw = (long long)in_sizes[0] / 2;
    if (nw > (1 << 20)) nw = 1 << 20;
    int nh = E0 > (1 << 16) ? (1 << 16) : E0;
    k_probe<<<256, 256, 0, stream>>>((const unsigned*)x_raw, nw, (const int*)eidx, nh,
                                     fcnt, iflag);

    // CSR build
    k_count<<<(E + 255) / 256, 256, 0, stream>>>(eidx, iflag, E0, N, deg);
    k_scan<<<1, 1024, 0, stream>>>(deg, rowptr, N);
    k_scatter<<<(E + 255) / 256, 256, 0, stream>>>(eidx, iflag, E0, N, rowptr, cursor,
                                                   csr_src);

    // input normalization: full convert only if fp32; tail pad always
    k_tobf16<<<1024, 256, 0, stream>>>(x_raw, fcnt, xb, (long long)N * K,
                                       (long long)Mpad * K);
    k_tail<<<64, 256, 0, stream>>>(x_raw, fcnt, xtail, nfull * 128, N, K);
    k_transpose<<<(K * C1 + 255) / 256, 256, 0, stream>>>(W1, fcnt, W1t, K, C1);
    k_transpose<<<(C1 * C2 + 255) / 256, 256, 0, stream>>>(W2, fcnt, W2t, C1, C2);

    // layer 1
    dim3 g1(Mpad / 128, C1 / 128);
    k_gemm<128, true><<<g1, 256, 0, stream>>>(x_raw, xb, xtail, fcnt, W1t, h1,
                                              N, C1, K, nfull);
    k_al<<<(N * H1 + 255) / 256, 256, 0, stream>>>(h1, as1, ad1, fcnt, al1s, al1d, N, H1);
    k_agg<512, 4, true, false><<<(N + 3) / 4, 256, 0, stream>>>(
        h1, al1s, al1d, rowptr, csr_src, b1, fcnt, hagg, N, E);

    // layer 2
    dim3 g2(Mpad / 128, C2 / 64);
    k_gemm<64, false><<<g2, 256, 0, stream>>>(hagg, nullptr, nullptr, fcnt, W2t, h2,
                                              N, C2, C1, 0);
    k_al<<<(N + 255) / 256, 256, 0, stream>>>(h2, as2, ad2, fcnt, al2s, al2d, N, 1);
    k_agg<128, 1, false, true><<<(N + 3) / 4, 256, 0, stream>>>(
        h2, al2s, al2d, rowptr, csr_src, b2, fcnt, d_out, N, E);
}

// Round 7
// 317.410 us; speedup vs baseline: 1.0293x; 1.0293x over previous
//
#include <hip/hip_runtime.h>
#include <hip/hip_bf16.h>

typedef __hip_bfloat16 bf16;
typedef __bf16 bf16x8 __attribute__((ext_vector_type(8)));
typedef float f32x4 __attribute__((ext_vector_type(4)));

#define NEG_SLOPE 0.2f
#define F32_THRESH 256

// ---------------- helpers ----------------------------------------------------

__device__ __forceinline__ bool is_f32(const int* fcnt) { return *fcnt > F32_THRESH; }

__device__ __forceinline__ float ld_f(const void* p, long long i, bool f32) {
    return f32 ? ((const float*)p)[i] : __bfloat162float(((const bf16*)p)[i]);
}

__device__ __forceinline__ float b2f(unsigned hs) {
    return __uint_as_float(hs << 16);
}

__device__ __forceinline__ unsigned pack_bf2(float a, float b) {
    union { bf16 h[2]; unsigned u; } p;
    p.h[0] = __float2bfloat16(a);
    p.h[1] = __float2bfloat16(b);
    return p.u;
}

__device__ __forceinline__ void load_lds16(const void* g, void* l) {
    __builtin_amdgcn_global_load_lds(
        (const __attribute__((address_space(1))) void*)g,
        (__attribute__((address_space(3))) void*)l, 16, 0, 0);
}

// feature-vector fragment per lane: 8 bf16 (uint4) or 2 bf16 (unsigned)
template <int CPL> struct FV;
template <> struct FV<8> {
    uint4 v;
    __device__ __forceinline__ void load(const bf16* p) { v = *(const uint4*)p; }
    __device__ __forceinline__ void fma(float* acc, float w) const {
        unsigned uu[4] = {v.x, v.y, v.z, v.w};
#pragma unroll
        for (int q = 0; q < 4; q++) {
            acc[2 * q] += w * b2f(uu[q] & 0xFFFFu);
            acc[2 * q + 1] += w * b2f(uu[q] >> 16);
        }
    }
};
template <> struct FV<2> {
    unsigned v;
    __device__ __forceinline__ void load(const bf16* p) { v = *(const unsigned*)p; }
    __device__ __forceinline__ void fma(float* acc, float w) const {
        acc[0] += w * b2f(v & 0xFFFFu);
        acc[1] += w * b2f(v >> 16);
    }
};

// ---------------- probe: dtype sniff + int-width detect ---------------------

__global__ void k_probe(const unsigned* xw, long long nw, const int* idx, int n_half,
                        int* cnt, int* iflag) {
    long long t = blockIdx.x * (long long)blockDim.x + threadIdx.x;
    long long stride = (long long)gridDim.x * blockDim.x;
    int c = 0;
    for (long long i = t; i < nw; i += stride)
        if ((xw[i] & 0x7F80u) == 0x7F80u) c++;
    if (c) atomicAdd(cnt, c);
    int any = 0;
    for (long long i = t; i < n_half; i += stride)
        if (idx[2 * i + 1] != 0) any = 1;
    if (any) atomicOr(iflag, 1);
}

// ---------------- CSR build (hardened) --------------------------------------

__device__ __forceinline__ int edge_val(const void* idx, long long i, int is64) {
    return is64 ? (int)((const long long*)idx)[i] : ((const int*)idx)[i];
}

__global__ void k_count(const void* idx, const int* iflag, int E0, int N, int* deg) {
    int e = blockIdx.x * blockDim.x + threadIdx.x;
    if (e >= E0 + N) return;
    int is64 = (*iflag == 0);
    int d = (e < E0) ? edge_val(idx, (long long)E0 + e, is64) : (e - E0);
    if ((unsigned)d >= (unsigned)N) d = 0;
    atomicAdd(&deg[d], 1);
}

__global__ __launch_bounds__(1024) void k_scan(const int* deg, int* rowptr, int N) {
    __shared__ int part[1024];
    int t = threadIdx.x;
    int chunk = (N + 1023) / 1024;
    int s = t * chunk, e = min(N, s + chunk);
    int sum = 0;
    for (int i = s; i < e; i++) sum += deg[i];
    part[t] = sum;
    __syncthreads();
    for (int off = 1; off < 1024; off <<= 1) {
        int v = (t >= off) ? part[t - off] : 0;
        __syncthreads();
        part[t] += v;
        __syncthreads();
    }
    int run = (t == 0) ? 0 : part[t - 1];
    for (int i = s; i < e; i++) { rowptr[i] = run; run += deg[i]; }
    if (t == 1023) rowptr[N] = part[1023];
}

__global__ void k_scatter(const void* idx, const int* iflag, int E0, int N,
                          const int* rowptr, int* cursor, int* csr_src) {
    int e = blockIdx.x * blockDim.x + threadIdx.x;
    if (e >= E0 + N) return;
    int is64 = (*iflag == 0);
    int s, d;
    if (e < E0) {
        s = edge_val(idx, e, is64);
        d = edge_val(idx, (long long)E0 + e, is64);
    } else {
        s = d = e - E0;
    }
    if ((unsigned)s >= (unsigned)N) s = 0;
    if ((unsigned)d >= (unsigned)N) d = 0;
    int pos = rowptr[d] + atomicAdd(&cursor[d], 1);
    if ((unsigned)pos < (unsigned)(E0 + N)) csr_src[pos] = s;
}

// ---------------- fused prep: tobf16 / tail pad / W transposes / hagg pad ---
// Role-partitioned by blockIdx.x. All roles independent (no syncs needed).

__global__ void k_prep(const void* x, const int* fcnt, bf16* xb, bf16* xtail,
                       const void* W1, bf16* W1t, const void* W2, bf16* W2t,
                       bf16* hpad, int hpad_elems, int N, int K, int C1, int C2,
                       int R0, long long n_valid, long long n_total) {
    const int b = blockIdx.x;
    const int tid = threadIdx.x;
    const bool f32 = is_f32(fcnt);
    if (b < 512) {
        // role 0: x fp32 -> bf16 packed copy (skip entirely when bf16 input)
        if (!f32) return;
        long long n8 = n_total / 8;
        for (long long i = (long long)b * 256 + tid; i < n8; i += 512LL * 256) {
            long long base = i * 8;
            uint4 out;
            if (base + 8 <= n_valid) {
                const float4* s4 = (const float4*)x;
                float4 x0 = s4[i * 2], x1 = s4[i * 2 + 1];
                out.x = pack_bf2(x0.x, x0.y);
                out.y = pack_bf2(x0.z, x0.w);
                out.z = pack_bf2(x1.x, x1.y);
                out.w = pack_bf2(x1.z, x1.w);
            } else {
                bf16 tmp[8];
#pragma unroll
                for (int j = 0; j < 8; j++) {
                    long long k = base + j;
                    tmp[j] = (k < n_valid) ? __float2bfloat16(ld_f(x, k, true))
                                           : __float2bfloat16(0.f);
                }
                out = *(uint4*)tmp;
            }
            ((uint4*)xb)[i] = out;
        }
    } else if (b < 528) {
        // role 1: 128-row tail pad of x (both dtypes)
        int total = 128 * K;
        for (int i = (b - 512) * 256 + tid; i < total; i += 16 * 256) {
            int r = i / K;
            long long src = (long long)(R0 + r) * K + (i - r * K);
            xtail[i] = (R0 + r < N) ? __float2bfloat16(ld_f(x, src, f32))
                                    : __float2bfloat16(0.f);
        }
    } else if (b < 656) {
        // role 2: W1t = W1^T
        int total = K * C1;
        for (int i = (b - 528) * 256 + tid; i < total; i += 128 * 256) {
            int k = i / C1, n = i - k * C1;
            W1t[(size_t)n * K + k] = __float2bfloat16(ld_f(W1, i, f32));
        }
    } else if (b < 688) {
        // role 3: W2t = W2^T
        int total = C1 * C2;
        for (int i = (b - 656) * 256 + tid; i < total; i += 32 * 256) {
            int k = i / C2, n = i - k * C2;
            W2t[(size_t)n * C1 + k] = __float2bfloat16(ld_f(W2, i, f32));
        }
    } else {
        // role 4: zero hagg pad rows
        for (int i = (b - 688) * 256 + tid; i < hpad_elems; i += 16 * 256)
            hpad[i] = __float2bfloat16(0.f);
    }
}

// ---------------- attention logits (vectorized) -----------------------------

__global__ void k_al(const bf16* __restrict__ h, const void* a_s, const void* a_d,
                     const int* fcnt, float* als, float* ald, int N, int H) {
    __shared__ float sa[512], sd[512];
    const int HC = H * 128;
    bool f32 = is_f32(fcnt);
    for (int i = threadIdx.x; i < HC; i += blockDim.x) {
        sa[i] = ld_f(a_s, i, f32);
        sd[i] = ld_f(a_d, i, f32);
    }
    __syncthreads();
    int i = blockIdx.x * blockDim.x + threadIdx.x;
    if (i >= N * H) return;
    int n = i / H, hh = i % H;
    const uint4* row = (const uint4*)(h + (size_t)n * HC + hh * 128);
    float s = 0.f, d = 0.f;
#pragma unroll
    for (int q = 0; q < 16; q++) {
        uint4 u = row[q];
        unsigned uu[4] = {u.x, u.y, u.z, u.w};
#pragma unroll
        for (int t = 0; t < 4; t++) {
            float v0 = b2f(uu[t] & 0xFFFFu), v1 = b2f(uu[t] >> 16);
            int c = hh * 128 + q * 8 + t * 2;
            s += v0 * sa[c] + v1 * sa[c + 1];
            d += v0 * sd[c] + v1 * sd[c + 1];
        }
    }
    als[i] = s;
    ald[i] = d;
}

// ---------------- MFMA GEMM (m97-style): C[M,Nn] = A @ Bt^T -----------------

template <int BN, bool SEL>
__global__ __launch_bounds__(256) void k_gemm(const void* Araw, const bf16* Aconv,
                                              const bf16* Atail, const int* fcnt,
                                              const bf16* __restrict__ Bt,
                                              bf16* __restrict__ C,
                                              int M, int Nn, int K, int nfull) {
    constexpr int BM = 128, BK = 32;
    constexpr int NT = BN / 32;
    const int m0 = blockIdx.x * BM;
    const int n0 = blockIdx.y * BN;
    __shared__ __bf16 As[BM][BK];
    __shared__ __bf16 Bs[BN][BK];
    const int tid = threadIdx.x;
    const int wave = tid >> 6;
    const int lane = tid & 63;
    const int wm = (wave & 1) * 64;
    const int wn = (wave >> 1) * (NT * 16);
    const int lm = lane & 15;
    const int quad = lane >> 4;
    const int srow = tid >> 2;
    const int scol = (tid & 3) * 8;

    f32x4 acc[4][NT];
#pragma unroll
    for (int mt = 0; mt < 4; mt++)
#pragma unroll
        for (int nt = 0; nt < NT; nt++) acc[mt][nt] = (f32x4){0.f, 0.f, 0.f, 0.f};

    const bf16* Abase;
    int arow0;
    if (SEL) {
        const bf16* Asel = is_f32(fcnt) ? Aconv : (const bf16*)Araw;
        if ((int)blockIdx.x < nfull) { Abase = Asel; arow0 = m0; }
        else { Abase = Atail; arow0 = 0; }
    } else {
        Abase = (const bf16*)Araw;
        arow0 = m0;
    }

    const char* Ab = (const char*)(Abase + (size_t)(arow0 + srow) * K + scol);
    const char* Bb = (const char*)(Bt + (size_t)(n0 + srow) * K + scol);
    char* ldsA = (char*)&As[0][0] + wave * 1024;
    char* ldsB = (char*)&Bs[0][0] + wave * 1024;
    const size_t rstep = (size_t)64 * K * 2;

    for (int k0 = 0; k0 < K; k0 += BK) {
        __syncthreads();
        const size_t kb = (size_t)k0 * 2;
        load_lds16(Ab + kb, ldsA);
        load_lds16(Ab + kb + rstep, ldsA + 4096);
        load_lds16(Bb + kb, ldsB);
        if (BN == 128) load_lds16(Bb + kb + rstep, ldsB + 4096);
        __syncthreads();
        bf16x8 af[4], bfv[NT];
#pragma unroll
        for (int mt = 0; mt < 4; mt++)
            af[mt] = *(const bf16x8*)&As[wm + mt * 16 + lm][quad * 8];
#pragma unroll
        for (int nt = 0; nt < NT; nt++)
            bfv[nt] = *(const bf16x8*)&Bs[wn + nt * 16 + lm][quad * 8];
#pragma unroll
        for (int mt = 0; mt < 4; mt++)
#pragma unroll
            for (int nt = 0; nt < NT; nt++)
                acc[mt][nt] = __builtin_amdgcn_mfma_f32_16x16x32_bf16(
                    af[mt], bfv[nt], acc[mt][nt], 0, 0, 0);
    }

#pragma unroll
    for (int mt = 0; mt < 4; mt++) {
        int rb = m0 + wm + mt * 16 + quad * 4;
#pragma unroll
        for (int nt = 0; nt < NT; nt++) {
            int col = n0 + wn + nt * 16 + lm;
#pragma unroll
            for (int r = 0; r < 4; r++) {
                int row = rb + r;
                if (row < M) C[(size_t)row * Nn + col] = __float2bfloat16(acc[mt][nt][r]);
            }
        }
    }
}

// ---------------- per-dst aggregation: wave-per-node, software-pipelined ----
// 3-stage register rotation: indices(b+2) | als+feat(b+1) | compute(b).
// Tail batches are full-width with weight masks (all loads stay valid).

template <int C, int H, bool ELU, bool DYN_OUT>
__global__ __launch_bounds__(256) void k_agg(
    const bf16* __restrict__ feat, const float* __restrict__ als,
    const float* __restrict__ ald, const int* __restrict__ rowptr,
    const int* __restrict__ csr_src, const void* bias, const int* fcnt,
    void* outp, int N, int E) {
    constexpr int CPL = C / 64;
    constexpr int Ch = C / H;
    const int wave = threadIdx.x >> 6;
    const int lane = threadIdx.x & 63;
    const int n = blockIdx.x * 4 + wave;
    if (n >= N) return;
    const int c0 = lane * CPL;
    const int head = c0 / Ch;

    int start = rowptr[n];
    if (start < 0) start = 0;
    int end = rowptr[n + 1];
    if (end > E) end = E;
    int deg = end - start;
    if (deg < 0) deg = 0;

    const float aldn = ald[(size_t)n * H + head];
    float acc[CPL] = {};
    float psum = 0.f;

    if (deg > 0) {
        const int nb = (deg + 3) >> 2;

        auto load_idx = [&](int b, int* s, float* m) {
#pragma unroll
            for (int j = 0; j < 4; j++) {
                int e = b * 4 + j;
                bool v = e < deg;
                int sv = csr_src[start + (v ? e : 0)];
                if ((unsigned)sv >= (unsigned)N) sv = 0;
                s[j] = sv;
                m[j] = v ? 1.f : 0.f;
            }
        };
        auto load_data = [&](const int* s, float* a, FV<CPL>* f) {
#pragma unroll
            for (int j = 0; j < 4; j++) {
                a[j] = als[(size_t)s[j] * H + head];
                f[j].load(feat + (size_t)s[j] * C + c0);
            }
        };

        int sP[4];
        float mP[4];
        float aC[4], mC[4];
        FV<CPL> fC[4];

        load_idx(0, sP, mP);
        load_data(sP, aC, fC);
#pragma unroll
        for (int j = 0; j < 4; j++) mC[j] = mP[j];
        if (nb > 1) load_idx(1, sP, mP);

        for (int b = 0;; b++) {
            float aN[4], mN[4];
            FV<CPL> fN[4];
            bool more = (b + 1) < nb;
            if (more) {
                load_data(sP, aN, fN);
#pragma unroll
                for (int j = 0; j < 4; j++) mN[j] = mP[j];
                if (b + 2 < nb) load_idx(b + 2, sP, mP);
            }
            // compute batch b
#pragma unroll
            for (int j = 0; j < 4; j++) {
                float l = aC[j] + aldn;
                l = l > 0.f ? l : NEG_SLOPE * l;
                float w = mC[j] * __expf(fminf(l, 60.f));
                psum += w;
                fC[j].fma(acc, w);
            }
            if (!more) break;
#pragma unroll
            for (int j = 0; j < 4; j++) {
                aC[j] = aN[j];
                mC[j] = mN[j];
                fC[j] = fN[j];
            }
        }
    }

    const float dn = psum + 1e-16f;
    const bool f32 = is_f32(fcnt);
#pragma unroll
    for (int j = 0; j < CPL; j++) {
        float v = acc[j] / dn + ld_f(bias, c0 + j, f32);
        if (ELU) v = v > 0.f ? v : expf(v) - 1.f;
        size_t oi = (size_t)n * C + c0 + j;
        if (DYN_OUT && f32) ((float*)outp)[oi] = v;
        else ((bf16*)outp)[oi] = __float2bfloat16(v);
    }
}

// ---------------- launch -----------------------------------------------------

extern "C" void kernel_launch(void* const* d_in, const int* in_sizes, int n_in,
                              void* d_out, int out_size, void* d_ws, size_t ws_size,
                              hipStream_t stream) {
    const int N = in_sizes[0] / 512;  // 20000
    const int K = 512;
    const int C1 = 512;
    const int C2 = 128;
    const int H1 = 4;
    const int E0 = in_sizes[1] / 2;   // 320000
    const int E = E0 + N;
    const int Mpad = (N + 127) / 128 * 128;  // 20096
    const int nfull = N / 128;               // full 128-row tiles

    const void* x_raw = d_in[0];
    const void* eidx = d_in[1];
    const void* W1 = d_in[2];
    const void* as1 = d_in[3];
    const void* ad1 = d_in[4];
    const void* b1 = d_in[5];
    const void* W2 = d_in[6];
    const void* as2 = d_in[7];
    const void* ad2 = d_in[8];
    const void* b2 = d_in[9];

    char* ws = (char*)d_ws;
    size_t off = 0;
    auto take = [&](size_t bytes) {
        size_t r = off;
        off += (bytes + 255) & ~(size_t)255;
        return r;
    };
    bf16* xb     = (bf16*)(ws + take((size_t)Mpad * K * 2));  // fp32 path; reused for h2
    bf16* xtail  = (bf16*)(ws + take((size_t)128 * K * 2));
    bf16* h1     = (bf16*)(ws + take((size_t)N * C1 * 2));
    bf16* hagg   = (bf16*)(ws + take((size_t)Mpad * C1 * 2));
    bf16* W1t    = (bf16*)(ws + take((size_t)K * C1 * 2));
    bf16* W2t    = (bf16*)(ws + take((size_t)C1 * C2 * 2));
    float* al1s  = (float*)(ws + take((size_t)N * H1 * 4));
    float* al1d  = (float*)(ws + take((size_t)N * H1 * 4));
    int* rowptr  = (int*)(ws + take((size_t)(N + 1) * 4));
    int* csr_src = (int*)(ws + take((size_t)E * 4));
    // contiguous zero-init: deg(N), cursor(N), iflag, fcnt
    int* deg     = (int*)(ws + take((size_t)(2 * N + 2) * 4));
    int* cursor  = deg + N;
    int* iflag   = deg + 2 * N;
    int* fcnt    = deg + 2 * N + 1;
    bf16* h2     = xb;     // alias: xb dead after gemm1
    float* al2s  = al1s;   // alias: al1 dead after agg1
    float* al2d  = al1d;
    if (off > ws_size) return;

    hipMemsetAsync(deg, 0, (size_t)(2 * N + 2) * 4, stream);

    // probes (capped scans)
    long long nw = (long long)in_sizes[0] / 2;
    if (nw > (1 << 20)) nw = 1 << 20;
    int nh = E0 > (1 << 16) ? (1 << 16) : E0;
    k_probe<<<256, 256, 0, stream>>>((const unsigned*)x_raw, nw, (const int*)eidx, nh,
                                     fcnt, iflag);

    // CSR build
    k_count<<<(E + 255) / 256, 256, 0, stream>>>(eidx, iflag, E0, N, deg);
    k_scan<<<1, 1024, 0, stream>>>(deg, rowptr, N);
    k_scatter<<<(E + 255) / 256, 256, 0, stream>>>(eidx, iflag, E0, N, rowptr, cursor,
                                                   csr_src);

    // fused prep: x convert (fp32 only) + tail pad + W transposes + hagg pad
    k_prep<<<704, 256, 0, stream>>>(x_raw, fcnt, xb, xtail, W1, W1t, W2, W2t,
                                    hagg + (size_t)N * C1, (Mpad - N) * C1,
                                    N, K, C1, C2, nfull * 128,
                                    (long long)N * K, (long long)Mpad * K);

    // layer 1
    dim3 g1(Mpad / 128, C1 / 128);
    k_gemm<128, true><<<g1, 256, 0, stream>>>(x_raw, xb, xtail, fcnt, W1t, h1,
                                              N, C1, K, nfull);
    k_al<<<(N * H1 + 255) / 256, 256, 0, stream>>>(h1, as1, ad1, fcnt, al1s, al1d, N, H1);
    k_agg<512, 4, true, false><<<(N + 3) / 4, 256, 0, stream>>>(
        h1, al1s, al1d, rowptr, csr_src, b1, fcnt, hagg, N, E);

    // layer 2
    dim3 g2(Mpad / 128, C2 / 64);
    k_gemm<64, false><<<g2, 256, 0, stream>>>(hagg, nullptr, nullptr, fcnt, W2t, h2,
                                              N, C2, C1, 0);
    k_al<<<(N + 255) / 256, 256, 0, stream>>>(h2, as2, ad2, fcnt, al2s, al2d, N, 1);
    k_agg<128, 1, false, true><<<(N + 3) / 4, 256, 0, stream>>>(
        h2, al2s, al2d, rowptr, csr_src, b2, fcnt, d_out, N, E);
}

// Round 8
// 316.220 us; speedup vs baseline: 1.0331x; 1.0038x over previous
//
#include <hip/hip_runtime.h>
#include <hip/hip_bf16.h>

typedef __hip_bfloat16 bf16;
typedef __bf16 bf16x8 __attribute__((ext_vector_type(8)));
typedef float f32x4 __attribute__((ext_vector_type(4)));

#define NEG_SLOPE 0.2f
#define F32_THRESH 256

// ---------------- helpers ----------------------------------------------------

__device__ __forceinline__ bool is_f32(const int* fcnt) { return *fcnt > F32_THRESH; }

__device__ __forceinline__ float ld_f(const void* p, long long i, bool f32) {
    return f32 ? ((const float*)p)[i] : __bfloat162float(((const bf16*)p)[i]);
}

__device__ __forceinline__ float b2f(unsigned hs) {
    return __uint_as_float(hs << 16);
}

__device__ __forceinline__ unsigned pack_bf2(float a, float b) {
    union { bf16 h[2]; unsigned u; } p;
    p.h[0] = __float2bfloat16(a);
    p.h[1] = __float2bfloat16(b);
    return p.u;
}

__device__ __forceinline__ void load_lds16(const void* g, void* l) {
    __builtin_amdgcn_global_load_lds(
        (const __attribute__((address_space(1))) void*)g,
        (__attribute__((address_space(3))) void*)l, 16, 0, 0);
}

// feature-vector fragment per lane: 8 bf16 (uint4) or 2 bf16 (unsigned)
template <int CPL> struct FV;
template <> struct FV<8> {
    uint4 v;
    __device__ __forceinline__ void load(const bf16* p) { v = *(const uint4*)p; }
    __device__ __forceinline__ void fma(float* acc, float w) const {
        unsigned uu[4] = {v.x, v.y, v.z, v.w};
#pragma unroll
        for (int q = 0; q < 4; q++) {
            acc[2 * q] += w * b2f(uu[q] & 0xFFFFu);
            acc[2 * q + 1] += w * b2f(uu[q] >> 16);
        }
    }
};
template <> struct FV<2> {
    unsigned v;
    __device__ __forceinline__ void load(const bf16* p) { v = *(const unsigned*)p; }
    __device__ __forceinline__ void fma(float* acc, float w) const {
        acc[0] += w * b2f(v & 0xFFFFu);
        acc[1] += w * b2f(v >> 16);
    }
};

// ---------------- probe: dtype sniff + int-width detect ---------------------

__global__ void k_probe(const unsigned* xw, long long nw, const int* idx, int n_half,
                        int* cnt, int* iflag) {
    long long t = blockIdx.x * (long long)blockDim.x + threadIdx.x;
    long long stride = (long long)gridDim.x * blockDim.x;
    int c = 0;
    for (long long i = t; i < nw; i += stride)
        if ((xw[i] & 0x7F80u) == 0x7F80u) c++;
    if (c) atomicAdd(cnt, c);
    int any = 0;
    for (long long i = t; i < n_half; i += stride)
        if (idx[2 * i + 1] != 0) any = 1;
    if (any) atomicOr(iflag, 1);
}

// ---------------- CSR build (hardened) --------------------------------------

__device__ __forceinline__ int edge_val(const void* idx, long long i, int is64) {
    return is64 ? (int)((const long long*)idx)[i] : ((const int*)idx)[i];
}

__global__ void k_count(const void* idx, const int* iflag, int E0, int N, int* deg) {
    int e = blockIdx.x * blockDim.x + threadIdx.x;
    if (e >= E0 + N) return;
    int is64 = (*iflag == 0);
    int d = (e < E0) ? edge_val(idx, (long long)E0 + e, is64) : (e - E0);
    if ((unsigned)d >= (unsigned)N) d = 0;
    atomicAdd(&deg[d], 1);
}

__global__ __launch_bounds__(1024) void k_scan(const int* deg, int* rowptr, int N) {
    __shared__ int part[1024];
    int t = threadIdx.x;
    int chunk = (N + 1023) / 1024;
    int s = t * chunk, e = min(N, s + chunk);
    int sum = 0;
    for (int i = s; i < e; i++) sum += deg[i];
    part[t] = sum;
    __syncthreads();
    for (int off = 1; off < 1024; off <<= 1) {
        int v = (t >= off) ? part[t - off] : 0;
        __syncthreads();
        part[t] += v;
        __syncthreads();
    }
    int run = (t == 0) ? 0 : part[t - 1];
    for (int i = s; i < e; i++) { rowptr[i] = run; run += deg[i]; }
    if (t == 1023) rowptr[N] = part[1023];
}

__global__ void k_scatter(const void* idx, const int* iflag, int E0, int N,
                          const int* rowptr, int* cursor, int* csr_src) {
    int e = blockIdx.x * blockDim.x + threadIdx.x;
    if (e >= E0 + N) return;
    int is64 = (*iflag == 0);
    int s, d;
    if (e < E0) {
        s = edge_val(idx, e, is64);
        d = edge_val(idx, (long long)E0 + e, is64);
    } else {
        s = d = e - E0;
    }
    if ((unsigned)s >= (unsigned)N) s = 0;
    if ((unsigned)d >= (unsigned)N) d = 0;
    int pos = rowptr[d] + atomicAdd(&cursor[d], 1);
    if ((unsigned)pos < (unsigned)(E0 + N)) csr_src[pos] = s;
}

// ---------------- fused prep: tobf16 / tail pad / W transposes / hagg pad ---

__global__ void k_prep(const void* x, const int* fcnt, bf16* xb, bf16* xtail,
                       const void* W1, bf16* W1t, const void* W2, bf16* W2t,
                       bf16* hpad, int hpad_elems, int N, int K, int C1, int C2,
                       int R0, long long n_valid, long long n_total) {
    const int b = blockIdx.x;
    const int tid = threadIdx.x;
    const bool f32 = is_f32(fcnt);
    if (b < 512) {
        if (!f32) return;
        long long n8 = n_total / 8;
        for (long long i = (long long)b * 256 + tid; i < n8; i += 512LL * 256) {
            long long base = i * 8;
            uint4 out;
            if (base + 8 <= n_valid) {
                const float4* s4 = (const float4*)x;
                float4 x0 = s4[i * 2], x1 = s4[i * 2 + 1];
                out.x = pack_bf2(x0.x, x0.y);
                out.y = pack_bf2(x0.z, x0.w);
                out.z = pack_bf2(x1.x, x1.y);
                out.w = pack_bf2(x1.z, x1.w);
            } else {
                bf16 tmp[8];
#pragma unroll
                for (int j = 0; j < 8; j++) {
                    long long k = base + j;
                    tmp[j] = (k < n_valid) ? __float2bfloat16(ld_f(x, k, true))
                                           : __float2bfloat16(0.f);
                }
                out = *(uint4*)tmp;
            }
            ((uint4*)xb)[i] = out;
        }
    } else if (b < 528) {
        int total = 128 * K;
        for (int i = (b - 512) * 256 + tid; i < total; i += 16 * 256) {
            int r = i / K;
            long long src = (long long)(R0 + r) * K + (i - r * K);
            xtail[i] = (R0 + r < N) ? __float2bfloat16(ld_f(x, src, f32))
                                    : __float2bfloat16(0.f);
        }
    } else if (b < 656) {
        int total = K * C1;
        for (int i = (b - 528) * 256 + tid; i < total; i += 128 * 256) {
            int k = i / C1, n = i - k * C1;
            W1t[(size_t)n * K + k] = __float2bfloat16(ld_f(W1, i, f32));
        }
    } else if (b < 688) {
        int total = C1 * C2;
        for (int i = (b - 656) * 256 + tid; i < total; i += 32 * 256) {
            int k = i / C2, n = i - k * C2;
            W2t[(size_t)n * C1 + k] = __float2bfloat16(ld_f(W2, i, f32));
        }
    } else {
        for (int i = (b - 688) * 256 + tid; i < hpad_elems; i += 16 * 256)
            hpad[i] = __float2bfloat16(0.f);
    }
}

// ---------------- attention logits (vectorized) -----------------------------

__global__ void k_al(const bf16* __restrict__ h, const void* a_s, const void* a_d,
                     const int* fcnt, float* als, float* ald, int N, int H) {
    __shared__ float sa[512], sd[512];
    const int HC = H * 128;
    bool f32 = is_f32(fcnt);
    for (int i = threadIdx.x; i < HC; i += blockDim.x) {
        sa[i] = ld_f(a_s, i, f32);
        sd[i] = ld_f(a_d, i, f32);
    }
    __syncthreads();
    int i = blockIdx.x * blockDim.x + threadIdx.x;
    if (i >= N * H) return;
    int n = i / H, hh = i % H;
    const uint4* row = (const uint4*)(h + (size_t)n * HC + hh * 128);
    float s = 0.f, d = 0.f;
#pragma unroll
    for (int q = 0; q < 16; q++) {
        uint4 u = row[q];
        unsigned uu[4] = {u.x, u.y, u.z, u.w};
#pragma unroll
        for (int t = 0; t < 4; t++) {
            float v0 = b2f(uu[t] & 0xFFFFu), v1 = b2f(uu[t] >> 16);
            int c = hh * 128 + q * 8 + t * 2;
            s += v0 * sa[c] + v1 * sa[c + 1];
            d += v0 * sd[c] + v1 * sd[c + 1];
        }
    }
    als[i] = s;
    ald[i] = d;
}

// ---------------- MFMA GEMM (m97-style): C[M,Nn] = A @ Bt^T -----------------

template <int BN, bool SEL>
__global__ __launch_bounds__(256) void k_gemm(const void* Araw, const bf16* Aconv,
                                              const bf16* Atail, const int* fcnt,
                                              const bf16* __restrict__ Bt,
                                              bf16* __restrict__ C,
                                              int M, int Nn, int K, int nfull) {
    constexpr int BM = 128, BK = 32;
    constexpr int NT = BN / 32;
    const int m0 = blockIdx.x * BM;
    const int n0 = blockIdx.y * BN;
    __shared__ __bf16 As[BM][BK];
    __shared__ __bf16 Bs[BN][BK];
    const int tid = threadIdx.x;
    const int wave = tid >> 6;
    const int lane = tid & 63;
    const int wm = (wave & 1) * 64;
    const int wn = (wave >> 1) * (NT * 16);
    const int lm = lane & 15;
    const int quad = lane >> 4;
    const int srow = tid >> 2;
    const int scol = (tid & 3) * 8;

    f32x4 acc[4][NT];
#pragma unroll
    for (int mt = 0; mt < 4; mt++)
#pragma unroll
        for (int nt = 0; nt < NT; nt++) acc[mt][nt] = (f32x4){0.f, 0.f, 0.f, 0.f};

    const bf16* Abase;
    int arow0;
    if (SEL) {
        const bf16* Asel = is_f32(fcnt) ? Aconv : (const bf16*)Araw;
        if ((int)blockIdx.x < nfull) { Abase = Asel; arow0 = m0; }
        else { Abase = Atail; arow0 = 0; }
    } else {
        Abase = (const bf16*)Araw;
        arow0 = m0;
    }

    const char* Ab = (const char*)(Abase + (size_t)(arow0 + srow) * K + scol);
    const char* Bb = (const char*)(Bt + (size_t)(n0 + srow) * K + scol);
    char* ldsA = (char*)&As[0][0] + wave * 1024;
    char* ldsB = (char*)&Bs[0][0] + wave * 1024;
    const size_t rstep = (size_t)64 * K * 2;

    for (int k0 = 0; k0 < K; k0 += BK) {
        __syncthreads();
        const size_t kb = (size_t)k0 * 2;
        load_lds16(Ab + kb, ldsA);
        load_lds16(Ab + kb + rstep, ldsA + 4096);
        load_lds16(Bb + kb, ldsB);
        if (BN == 128) load_lds16(Bb + kb + rstep, ldsB + 4096);
        __syncthreads();
        bf16x8 af[4], bfv[NT];
#pragma unroll
        for (int mt = 0; mt < 4; mt++)
            af[mt] = *(const bf16x8*)&As[wm + mt * 16 + lm][quad * 8];
#pragma unroll
        for (int nt = 0; nt < NT; nt++)
            bfv[nt] = *(const bf16x8*)&Bs[wn + nt * 16 + lm][quad * 8];
#pragma unroll
        for (int mt = 0; mt < 4; mt++)
#pragma unroll
            for (int nt = 0; nt < NT; nt++)
                acc[mt][nt] = __builtin_amdgcn_mfma_f32_16x16x32_bf16(
                    af[mt], bfv[nt], acc[mt][nt], 0, 0, 0);
    }

#pragma unroll
    for (int mt = 0; mt < 4; mt++) {
        int rb = m0 + wm + mt * 16 + quad * 4;
#pragma unroll
        for (int nt = 0; nt < NT; nt++) {
            int col = n0 + wn + nt * 16 + lm;
#pragma unroll
            for (int r = 0; r < 4; r++) {
                int row = rb + r;
                if (row < M) C[(size_t)row * Nn + col] = __float2bfloat16(acc[mt][nt][r]);
            }
        }
    }
}

// ---------------- per-dst aggregation: wave-per-node, LDS-staged indices ----
// Lane j stages edge j's src index + per-head exp weights into a wave-private
// LDS slab (1 exp/edge/head, x5-padded conflict-free). Then a deg-long serial
// loop of INDEPENDENT dwordx4 gathers (addresses all known after staging).
// No __syncthreads anywhere (wave-private LDS, lgkmcnt-ordered). Denominator
// is each lane's own psum of broadcast weights — no reduction.

template <int C, int H, bool ELU, bool DYN_OUT>
__global__ __launch_bounds__(256) void k_agg(
    const bf16* __restrict__ feat, const float* __restrict__ als,
    const float* __restrict__ ald, const int* __restrict__ rowptr,
    const int* __restrict__ csr_src, const void* bias, const int* fcnt,
    void* outp, int N, int E) {
    constexpr int CPL = C / 64;
    constexpr int Ch = C / H;
    constexpr int WPAD = (H == 4) ? 5 : 1;
    const int wave = threadIdx.x >> 6;
    const int lane = threadIdx.x & 63;
    const int n = blockIdx.x * 4 + wave;
    const int c0 = lane * CPL;
    const int head = c0 / Ch;

    __shared__ float s_w[4][64 * WPAD];
    __shared__ int s_s[4][64];

    if (n >= N) return;

    int start = rowptr[n];
    if (start < 0) start = 0;
    int end = rowptr[n + 1];
    if (end > E) end = E;
    int deg = end - start;
    if (deg < 0) deg = 0;

    float aldn[H];
    if (H == 4) {
        float4 a4 = ((const float4*)ald)[n];
        aldn[0] = a4.x; aldn[1] = a4.y; aldn[2] = a4.z;
        if (H > 3) aldn[3] = a4.w;
    } else {
        aldn[0] = ald[n];
    }

    float acc[CPL] = {};
    float psum = 0.f;

    for (int base = 0; base < deg; base += 64) {
        int cnt = min(64, deg - base);
        // stage: lane j owns edge base+j
        if (lane < cnt) {
            int s = csr_src[start + base + lane];
            if ((unsigned)s >= (unsigned)N) s = 0;
            s_s[wave][lane] = s;
            if (H == 4) {
                float4 a4 = ((const float4*)als)[s];
                float aa[4] = {a4.x, a4.y, a4.z, a4.w};
#pragma unroll
                for (int h = 0; h < 4; h++) {
                    float l = aa[h] + aldn[h];
                    l = l > 0.f ? l : NEG_SLOPE * l;
                    s_w[wave][lane * 5 + h] = __expf(fminf(l, 60.f));
                }
            } else {
                float l = als[s] + aldn[0];
                l = l > 0.f ? l : NEG_SLOPE * l;
                s_w[wave][lane] = __expf(fminf(l, 60.f));
            }
        }
        // gather: independent loads, addresses known after staging
#pragma unroll 4
        for (int e = 0; e < cnt; e++) {
            int s = s_s[wave][e];
            float wl = (H == 4) ? s_w[wave][e * 5 + head] : s_w[wave][e];
            psum += wl;
            FV<CPL> f;
            f.load(feat + (size_t)s * C + c0);
            f.fma(acc, wl);
        }
    }

    const float dn = psum + 1e-16f;
    const bool f32 = is_f32(fcnt);
#pragma unroll
    for (int j = 0; j < CPL; j++) {
        float v = acc[j] / dn + ld_f(bias, c0 + j, f32);
        if (ELU) v = v > 0.f ? v : expf(v) - 1.f;
        size_t oi = (size_t)n * C + c0 + j;
        if (DYN_OUT && f32) ((float*)outp)[oi] = v;
        else ((bf16*)outp)[oi] = __float2bfloat16(v);
    }
}

// ---------------- launch -----------------------------------------------------

extern "C" void kernel_launch(void* const* d_in, const int* in_sizes, int n_in,
                              void* d_out, int out_size, void* d_ws, size_t ws_size,
                              hipStream_t stream) {
    const int N = in_sizes[0] / 512;  // 20000
    const int K = 512;
    const int C1 = 512;
    const int C2 = 128;
    const int H1 = 4;
    const int E0 = in_sizes[1] / 2;   // 320000
    const int E = E0 + N;
    const int Mpad = (N + 127) / 128 * 128;  // 20096
    const int nfull = N / 128;               // full 128-row tiles

    const void* x_raw = d_in[0];
    const void* eidx = d_in[1];
    const void* W1 = d_in[2];
    const void* as1 = d_in[3];
    const void* ad1 = d_in[4];
    const void* b1 = d_in[5];
    const void* W2 = d_in[6];
    const void* as2 = d_in[7];
    const void* ad2 = d_in[8];
    const void* b2 = d_in[9];

    char* ws = (char*)d_ws;
    size_t off = 0;
    auto take = [&](size_t bytes) {
        size_t r = off;
        off += (bytes + 255) & ~(size_t)255;
        return r;
    };
    bf16* xb     = (bf16*)(ws + take((size_t)Mpad * K * 2));  // fp32 path; reused for h2
    bf16* xtail  = (bf16*)(ws + take((size_t)128 * K * 2));
    bf16* h1     = (bf16*)(ws + take((size_t)N * C1 * 2));
    bf16* hagg   = (bf16*)(ws + take((size_t)Mpad * C1 * 2));
    bf16* W1t    = (bf16*)(ws + take((size_t)K * C1 * 2));
    bf16* W2t    = (bf16*)(ws + take((size_t)C1 * C2 * 2));
    float* al1s  = (float*)(ws + take((size_t)N * H1 * 4));
    float* al1d  = (float*)(ws + take((size_t)N * H1 * 4));
    int* rowptr  = (int*)(ws + take((size_t)(N + 1) * 4));
    int* csr_src = (int*)(ws + take((size_t)E * 4));
    // contiguous zero-init: deg(N), cursor(N), iflag, fcnt
    int* deg     = (int*)(ws + take((size_t)(2 * N + 2) * 4));
    int* cursor  = deg + N;
    int* iflag   = deg + 2 * N;
    int* fcnt    = deg + 2 * N + 1;
    bf16* h2     = xb;     // alias: xb dead after gemm1
    float* al2s  = al1s;   // alias: al1 dead after agg1
    float* al2d  = al1d;
    if (off > ws_size) return;

    hipMemsetAsync(deg, 0, (size_t)(2 * N + 2) * 4, stream);

    // probes (capped scans)
    long long nw = (long long)in_sizes[0] / 2;
    if (nw > (1 << 20)) nw = 1 << 20;
    int nh = E0 > (1 << 16) ? (1 << 16) : E0;
    k_probe<<<256, 256, 0, stream>>>((const unsigned*)x_raw, nw, (const int*)eidx, nh,
                                     fcnt, iflag);

    // CSR build
    k_count<<<(E + 255) / 256, 256, 0, stream>>>(eidx, iflag, E0, N, deg);
    k_scan<<<1, 1024, 0, stream>>>(deg, rowptr, N);
    k_scatter<<<(E + 255) / 256, 256, 0, stream>>>(eidx, iflag, E0, N, rowptr, cursor,
                                                   csr_src);

    // fused prep: x convert (fp32 only) + tail pad + W transposes + hagg pad
    k_prep<<<704, 256, 0, stream>>>(x_raw, fcnt, xb, xtail, W1, W1t, W2, W2t,
                                    hagg + (size_t)N * C1, (Mpad - N) * C1,
                                    N, K, C1, C2, nfull * 128,
                                    (long long)N * K, (long long)Mpad * K);

    // layer 1
    dim3 g1(Mpad / 128, C1 / 128);
    k_gemm<128, true><<<g1, 256, 0, stream>>>(x_raw, xb, xtail, fcnt, W1t, h1,
                                              N, C1, K, nfull);
    k_al<<<(N * H1 + 255) / 256, 256, 0, stream>>>(h1, as1, ad1, fcnt, al1s, al1d, N, H1);
    k_agg<512, 4, true, false><<<(N + 3) / 4, 256, 0, stream>>>(
        h1, al1s, al1d, rowptr, csr_src, b1, fcnt, hagg, N, E);

    // layer 2
    dim3 g2(Mpad / 128, C2 / 64);
    k_gemm<64, false><<<g2, 256, 0, stream>>>(hagg, nullptr, nullptr, fcnt, W2t, h2,
                                              N, C2, C1, 0);
    k_al<<<(N + 255) / 256, 256, 0, stream>>>(h2, as2, ad2, fcnt, al2s, al2d, N, 1);
    k_agg<128, 1, false, true><<<(N + 3) / 4, 256, 0, stream>>>(
        h2, al2s, al2d, rowptr, csr_src, b2, fcnt, d_out, N, E);
}